// Round 20
// baseline (805.380 us; speedup 1.0000x reference)
//
#include <hip/hip_runtime.h>
#include <stdint.h>

#define B_ 2
#define P_ 256
#define TL_ 1280
#define T_ 1536
#define H_ 1024
#define HEADS_ 16
#define HD_ 64
#define NL_ 2
#define V_ 32000
#define F_ 4096
#define BT_ (B_ * T_)

typedef __attribute__((ext_vector_type(4))) float f32x4;
typedef __attribute__((ext_vector_type(8))) short short8;
typedef __attribute__((ext_vector_type(4))) short short4v;

typedef __attribute__((address_space(3))) uint32_t lds_u32_t;
typedef const __attribute__((address_space(1))) uint32_t glb_u32_t;

__device__ inline void gload_lds16(const void* g, void* l) {
    __builtin_amdgcn_global_load_lds((glb_u32_t*)g, (lds_u32_t*)l, 16, 0, 0);
}

__device__ inline short f2bf(float f) {
    union { float f; unsigned u; } v; v.f = f;
    unsigned r = v.u + 0x7FFF + ((v.u >> 16) & 1);
    return (short)(r >> 16);
}

__device__ inline float bf2f(short s) {
    union { unsigned u; float f; } v;
    v.u = ((unsigned)(unsigned short)s) << 16;
    return v.f;
}

#define BAR() asm volatile("s_barrier" ::: "memory")
#define WAIT_VM0() asm volatile("s_waitcnt vmcnt(0)" ::: "memory")
#define WAIT_VM4() asm volatile("s_waitcnt vmcnt(4)" ::: "memory")
#define WAIT_VM8() asm volatile("s_waitcnt vmcnt(8)" ::: "memory")
#define WAIT_VM32() asm volatile("s_waitcnt vmcnt(32)" ::: "memory")
#define WAIT_VM36() asm volatile("s_waitcnt vmcnt(36)" ::: "memory")

// ---------------- fused weight transpose-convert: f32 [K,N] -> bf16 [N,K] ----
__global__ __launch_bounds__(256) void k_cvt_all(
    const float* __restrict__ Wq, const float* __restrict__ Wk,
    const float* __restrict__ Wv, const float* __restrict__ Wo,
    const float* __restrict__ W1, const float* __restrict__ W2,
    const float* __restrict__ Wh,
    short* __restrict__ WqkvT, short* __restrict__ WoT,
    short* __restrict__ W1T, short* __restrict__ W2T, short* __restrict__ WhT) {
    int id = blockIdx.x;
    const float* src;
    short* dst;
    int K, N;
    float scale = 1.f;
    if (id < 1536) {                       // qkv: 6 mats x 256 tiles
        int mat = id >> 8;
        int tile = id & 255;
        int l = mat / 3, which = mat - l * 3;
        src = (which == 0 ? Wq : which == 1 ? Wk : Wv) + (size_t)l * H_ * H_;
        dst = WqkvT + (size_t)(l * 3 + which) * H_ * H_;
        K = H_; N = H_;
        if (which == 0) scale = 0.125f;
        id = tile;
    } else if (id < 2048) {                // wo: 2 x 256
        int rel = id - 1536;
        int l = rel >> 8;
        src = Wo + (size_t)l * H_ * H_;
        dst = WoT + (size_t)l * H_ * H_;
        K = H_; N = H_;
        id = rel & 255;
    } else if (id < 4096) {                // w1: 2 x 1024
        int rel = id - 2048;
        int l = rel >> 10;
        src = W1 + (size_t)l * H_ * F_;
        dst = W1T + (size_t)l * H_ * F_;
        K = H_; N = F_;
        id = rel & 1023;
    } else if (id < 6144) {                // w2: 2 x 1024
        int rel = id - 4096;
        int l = rel >> 10;
        src = W2 + (size_t)l * F_ * H_;
        dst = W2T + (size_t)l * F_ * H_;
        K = F_; N = H_;
        id = rel & 1023;
    } else {                               // head: 8000 tiles
        id -= 6144;
        src = Wh; dst = WhT;
        K = H_; N = V_;
    }
    int ntn = N >> 6;
    int nb = (id % ntn) * 64, kb = (id / ntn) * 64;

    __shared__ float ts[64][65];
    int tid = threadIdx.x;
    int rr = tid >> 4, c4 = (tid & 15) * 4;
#pragma unroll
    for (int it = 0; it < 4; ++it) {
        int r = rr + it * 16;
        f32x4 v = __builtin_nontemporal_load(
            (const f32x4*)&src[(size_t)(kb + r) * N + nb + c4]);
        *(f32x4*)&ts[r][c4] = v;
    }
    __syncthreads();
    int wn = tid >> 2, ko = (tid & 3) * 16;
    short o[16];
#pragma unroll
    for (int j = 0; j < 16; ++j) o[j] = f2bf(ts[ko + j][wn] * scale);
    short* dp = &dst[(size_t)(nb + wn) * K + kb + ko];
    *(short8*)&dp[0] = *(short8*)&o[0];
    *(short8*)&dp[8] = *(short8*)&o[8];
}

// ---------------- embed + concat + first layernorm ---------------------------
__global__ __launch_bounds__(256) void k_embed_ln(const float* __restrict__ prefix,
                                                  const int* __restrict__ ids,
                                                  const float* __restrict__ emb,
                                                  const float* __restrict__ g,
                                                  const float* __restrict__ b,
                                                  float* __restrict__ x,
                                                  short* __restrict__ h) {
    int r = blockIdx.x;
    int bb = r / T_, t = r % T_;
    const float* src = (t < P_) ? (prefix + (size_t)(bb * P_ + t) * H_)
                                : (emb + (size_t)ids[bb * TL_ + (t - P_)] * H_);
    int tid = threadIdx.x;
    f32x4 v = *(const f32x4*)&src[tid * 4];
    *(f32x4*)&x[(size_t)r * H_ + tid * 4] = v;
    float s = v[0] + v[1] + v[2] + v[3];
    float sq = v[0] * v[0] + v[1] * v[1] + v[2] * v[2] + v[3] * v[3];
#pragma unroll
    for (int off = 32; off; off >>= 1) {
        s += __shfl_down(s, off, 64);
        sq += __shfl_down(sq, off, 64);
    }
    __shared__ float red[10];
    int wid = tid >> 6;
    if ((tid & 63) == 0) { red[wid] = s; red[4 + wid] = sq; }
    __syncthreads();
    if (tid == 0) {
        float S = red[0] + red[1] + red[2] + red[3];
        float SQ = red[4] + red[5] + red[6] + red[7];
        float mu = S * (1.0f / H_);
        float var = SQ * (1.0f / H_) - mu * mu;
        red[8] = mu;
        red[9] = rsqrtf(var + 1e-5f);
    }
    __syncthreads();
    float mu = red[8], rstd = red[9];
    short o[4];
#pragma unroll
    for (int j = 0; j < 4; ++j)
        o[j] = f2bf((v[j] - mu) * rstd * g[tid * 4 + j] + b[tid * 4 + j]);
    *(short4v*)&h[(size_t)r * H_ + tid * 4] = *(short4v*)o;
}

// -------- x += p0+p1+p2+p3 (bf16 split-K slabs), then LN -> bf16 -------------
__global__ __launch_bounds__(256) void k_add_ln(float* __restrict__ x,
                                                const short* __restrict__ p,
                                                const float* __restrict__ g,
                                                const float* __restrict__ b,
                                                short* __restrict__ out) {
    int r = blockIdx.x;
    int tid = threadIdx.x;
    size_t base = (size_t)r * H_ + tid * 4;
    f32x4 v = *(f32x4*)&x[base];
#pragma unroll
    for (int sl = 0; sl < 4; ++sl) {
        short4v a = *(const short4v*)&p[(size_t)sl * BT_ * H_ + base];
#pragma unroll
        for (int j = 0; j < 4; ++j) v[j] += bf2f(a[j]);
    }
    *(f32x4*)&x[base] = v;
    float s = v[0] + v[1] + v[2] + v[3];
    float sq = v[0] * v[0] + v[1] * v[1] + v[2] * v[2] + v[3] * v[3];
#pragma unroll
    for (int off = 32; off; off >>= 1) {
        s += __shfl_down(s, off, 64);
        sq += __shfl_down(sq, off, 64);
    }
    __shared__ float red[10];
    int wid = tid >> 6;
    if ((tid & 63) == 0) { red[wid] = s; red[4 + wid] = sq; }
    __syncthreads();
    if (tid == 0) {
        float S = red[0] + red[1] + red[2] + red[3];
        float SQ = red[4] + red[5] + red[6] + red[7];
        float mu = S * (1.0f / H_);
        float var = SQ * (1.0f / H_) - mu * mu;
        red[8] = mu;
        red[9] = rsqrtf(var + 1e-5f);
    }
    __syncthreads();
    float mu = red[8], rstd = red[9];
    short o[4];
#pragma unroll
    for (int j = 0; j < 4; ++j)
        o[j] = f2bf((v[j] - mu) * rstd * g[tid * 4 + j] + b[tid * 4 + j]);
    *(short4v*)&out[base] = *(short4v*)o;
}

// ---------------- 128x128 GEMM, BK=64, DOUBLE-buffered -----------------------
// STORE: 0 = bf16 split-K partial slab, 1 = bf16 (+bias+silu), 3 = fused QKV
template <int STORE, bool HAS_BIAS, bool SILU, int NSPLIT>
__global__ __launch_bounds__(256) void k_gemm(const short* __restrict__ A,
                                              const short* __restrict__ Bt,
                                              const float* __restrict__ bias,
                                              void* __restrict__ outp,
                                              void* __restrict__ outp2,
                                              void* __restrict__ outp3,
                                              int M, int N, int K, float alpha) {
    __shared__ short SH[32768];   // 64 KiB
    int tid = threadIdx.x;
    int lane = tid & 63, w = tid >> 6;
    int wr = w >> 1, wc = w & 1;
    int nwg = gridDim.x;
    int mblocks = M >> 7;
    int cpx = nwg >> 3;
    int logical = (blockIdx.x & 7) * cpx + (blockIdx.x >> 3);
    int ks = 0;
    if (NSPLIT > 1) {
        int per = mblocks * (N >> 7);
        ks = logical / per;
        logical -= ks * per;
    }
    int rp = logical % mblocks, cp = logical / mblocks;
    int mbase = rp * 128, nbase = cp * 128;
    int Kh = K / NSPLIT;
    int lr = lane & 15, hi = lane >> 4;
    int lg = hi * 4;

    f32x4 acc[4][4] = {};

    const short* Ab = A + (size_t)mbase * K + (size_t)ks * Kh;
    const short* Bb = Bt + (size_t)nbase * K + (size_t)ks * Kh;

    int koffb[2];
    koffb[0] = ((hi) ^ (lr & 7)) << 4;
    koffb[1] = ((4 + hi) ^ (lr & 7)) << 4;
    int arowb[4], browb[4];
#pragma unroll
    for (int m = 0; m < 4; ++m) arowb[m] = (wr * 64 + m * 16 + lr) * 128;
#pragma unroll
    for (int n = 0; n < 4; ++n) browb[n] = (wc * 64 + n * 16 + lr) * 128;

    auto stage = [&](int t, int buf) {
        short* la = SH + buf * 8192;
        short* lb = SH + 16384 + buf * 8192;
#pragma unroll
        for (int c = 0; c < 4; ++c) {
            int S = tid + 256 * c;
            int r = S >> 3, ch = S & 7;
            int gofs = t * 64 + ((ch ^ (r & 7)) << 3);
            gload_lds16(Ab + (size_t)r * K + gofs, la + S * 8);
            gload_lds16(Bb + (size_t)r * K + gofs, lb + S * 8);
        }
    };

    int NT = Kh >> 6;
    stage(0, 0);
    WAIT_VM0();
    BAR();

    for (int t = 0; t < NT; ++t) {
        if (t + 1 < NT) stage(t + 1, (t + 1) & 1);
        const char* a = (const char*)(SH + (t & 1) * 8192);
        const char* b = (const char*)(SH + 16384 + (t & 1) * 8192);
        short8 af[2][4], bfr[2][4];
#pragma unroll
        for (int kk = 0; kk < 2; ++kk) {
#pragma unroll
            for (int m = 0; m < 4; ++m) af[kk][m] = *(const short8*)(a + arowb[m] + koffb[kk]);
#pragma unroll
            for (int n = 0; n < 4; ++n) bfr[kk][n] = *(const short8*)(b + browb[n] + koffb[kk]);
        }
        __builtin_amdgcn_s_setprio(1);
#pragma unroll
        for (int kk = 0; kk < 2; ++kk)
#pragma unroll
            for (int m = 0; m < 4; ++m)
#pragma unroll
                for (int n = 0; n < 4; ++n)
                    acc[m][n] = __builtin_amdgcn_mfma_f32_16x16x32_bf16(af[kk][m], bfr[kk][n], acc[m][n], 0, 0, 0);
        __builtin_amdgcn_s_setprio(0);
        if (t + 1 < NT) {
            WAIT_VM0();
            BAR();
        }
    }

    if (STORE == 3 && nbase >= 2048) {
        BAR();
        short* Tt = SH;
#pragma unroll
        for (int ni = 0; ni < 4; ++ni) {
            int c2 = wc * 64 + ni * 16 + lr;
#pragma unroll
            for (int mi = 0; mi < 4; ++mi)
#pragma unroll
                for (int j = 0; j < 4; ++j)
                    Tt[c2 * 136 + wr * 64 + mi * 16 + lg + j] = f2bf(acc[mi][ni][j]);
        }
        BAR();
        int c2 = tid >> 1;
        int half = (tid & 1) * 64;
        int cc = (nbase + c2) & 1023;
        int head = cc >> 6, hd = cc & 63;
        int bb = mbase / T_;
        int t0 = mbase - bb * T_;
        short* dst = (short*)outp3 +
                     ((size_t)(bb * HEADS_ + head) * HD_ + hd) * T_ + t0 + half;
#pragma unroll
        for (int r8 = 0; r8 < 8; ++r8)
            *(short8*)&dst[r8 * 8] = *(short8*)&Tt[c2 * 136 + half + r8 * 8];
        return;
    }

#pragma unroll
    for (int ni = 0; ni < 4; ++ni) {
        int col = nbase + wc * 64 + ni * 16 + lr;
        float bv = (HAS_BIAS && ks == 0) ? bias[col] : 0.f;
#pragma unroll
        for (int mi = 0; mi < 4; ++mi) {
#pragma unroll
            for (int j = 0; j < 4; ++j) {
                int row = mbase + wr * 64 + mi * 16 + lg + j;
                float vv = acc[mi][ni][j] * alpha + bv;
                if (SILU) vv = vv / (1.f + __expf(-vv));
                if (STORE == 0) {
                    ((short*)outp)[(size_t)ks * M * N + (size_t)row * N + col] = f2bf(vv);
                } else if (STORE == 1) {
                    ((short*)outp)[(size_t)row * N + col] = f2bf(vv);
                } else {
                    int seg = col >> 10;
                    int c = col & 1023;
                    if (seg == 0) {
                        ((short*)outp)[(size_t)row * H_ + c] = f2bf(vv);
                    } else {
                        ((short*)outp2)[(size_t)row * H_ + c] = f2bf(vv);
                    }
                }
            }
        }
    }
}

// ---------------- 8-phase 256x256 GEMM, PERSISTENT (grid 256) ----------------
// r20: STRIDE-256 tile walk (was contiguous chunks).  With chunks, an XCD's
// 32 blocks sat at different offsets of a 187-tile chunk -> ~15 concurrent
// B-panels (8 MB) thrashing the 4 MB L2 (FETCH 245 MB vs 72 ideal).  With
// t = g + i*256 all of an XCD's blocks work 32 CONSECUTIVE tiles -> 3-4
// panels (~2 MB) L2-resident; each panel is consumed within one wave.
// r18 slack waits + boundary prolog-before-stores unchanged.
// DO NOT cap registers below 256/wave (r3: spills, 7.5x slow).
__global__ __launch_bounds__(512, 2) void k_gemm8(const short* __restrict__ A,
                                                  const short* __restrict__ Bt,
                                                  float* __restrict__ C,
                                                  int M, int N, int K) {
    __shared__ short As[2 * 256 * 64];   // 64 KiB
    __shared__ short Bs[2 * 256 * 64];   // 64 KiB
    int tid = threadIdx.x;
    int lane = tid & 63, w = tid >> 6;
    int wr = w >> 2, wc = w & 3;
    int lr = lane & 15, hi = lane >> 4;

    int mtiles = M >> 8;
    int total = mtiles * (N >> 8);
    int g = ((blockIdx.x & 7) << 5) + (blockIdx.x >> 3);   // XCD-contiguous g
    int cnt = (total - g + 255) >> 8;                      // tiles at stride 256

    int r0 = tid >> 3;
    int gcol = ((tid & 7) ^ (r0 & 7)) * 8;
    int koff0 = (hi * 16) ^ ((lr & 7) << 4);
    int koff1 = (64 + hi * 16) ^ ((lr & 7) << 4);
    int arow[8], brow[4];
#pragma unroll
    for (int m = 0; m < 8; ++m) arow[m] = (wr * 128 + m * 16 + lr) * 128;
#pragma unroll
    for (int n = 0; n < 4; ++n) brow[n] = (wc * 64 + n * 16 + lr) * 128;

    f32x4 acc[8][4];
    short8 aF[4][2], bF[4][2];
    const char* Ac = (const char*)As;
    const char* Bc = (const char*)Bs;

    auto stage = [&](const short* Gb, char* Lb, int tau, int hf) {
        const short* g0 = Gb + (size_t)(hf * 128 + r0) * K + tau * 64 + gcol;
        char* l = Lb + (tau & 1) * 32768 + hf * 16384;
        gload_lds16(g0, l + tid * 16);
        gload_lds16(g0 + (size_t)64 * K, l + (tid + 512) * 16);
    };
    auto prolog = [&](const short* Ab, const short* Bb) {
        stage(Ab, (char*)As, 0, 0); stage(Ab, (char*)As, 0, 1);
        stage(Bb, (char*)Bs, 0, 0); stage(Bb, (char*)Bs, 0, 1);
        stage(Ab, (char*)As, 1, 0); stage(Ab, (char*)As, 1, 1);
        stage(Bb, (char*)Bs, 1, 0); stage(Bb, (char*)Bs, 1, 1);
    };
    auto lda4 = [&](const char* base, int roff) {
#pragma unroll
        for (int m = 0; m < 4; ++m) {
            aF[m][0] = *(const short8*)(base + arow[roff + m] + koff0);
            aF[m][1] = *(const short8*)(base + arow[roff + m] + koff1);
        }
    };
    auto ldb2 = [&](const char* base, int noff) {
#pragma unroll
        for (int n = 0; n < 2; ++n) {
            bF[noff + n][0] = *(const short8*)(base + brow[noff + n] + koff0);
            bF[noff + n][1] = *(const short8*)(base + brow[noff + n] + koff1);
        }
    };

#define MFMA_QUAD(MOFF, NOFF)                                                          \
    __builtin_amdgcn_s_setprio(1);                                                     \
    _Pragma("unroll") for (int m = 0; m < 4; ++m) {                                    \
        _Pragma("unroll") for (int n = 0; n < 2; ++n) {                                \
            acc[MOFF + m][NOFF + n] = __builtin_amdgcn_mfma_f32_16x16x32_bf16(         \
                aF[m][0], bF[NOFF + n][0], acc[MOFF + m][NOFF + n], 0, 0, 0);          \
            acc[MOFF + m][NOFF + n] = __builtin_amdgcn_mfma_f32_16x16x32_bf16(         \
                aF[m][1], bF[NOFF + n][1], acc[MOFF + m][NOFF + n], 0, 0, 0);          \
        }                                                                              \
    }                                                                                  \
    __builtin_amdgcn_s_setprio(0);

    int NK = K >> 6;
    int niters = NK >> 1;

    for (int i = 0; i < cnt; ++i) {
        int t0 = g + i * 256;
        int rp = t0 % mtiles, cp = t0 / mtiles;
        const short* Ab = A + (size_t)rp * 256 * K;
        const short* Bb = Bt + (size_t)cp * 256 * K;
        f32x4 zz = {0.f, 0.f, 0.f, 0.f};
#pragma unroll
        for (int m = 0; m < 8; ++m)
#pragma unroll
            for (int n = 0; n < 4; ++n) acc[m][n] = zz;

        if (i == 0) {
            prolog(Ab, Bb);
            WAIT_VM0();
            BAR();
        }

        for (int it = 0; it < niters; ++it) {
            bool st = it < niters - 1;
            int u2 = 2 * it + 2, v2 = 2 * it + 3;
            const char* a0 = Ac;            const char* b0 = Bc;
            const char* a1 = Ac + 32768;    const char* b1 = Bc + 32768;

            // ===== tile u (buf0), phases 1-4 =====
            lda4(a0, 0); ldb2(b0, 0);
            BAR();
            MFMA_QUAD(0, 0);
            BAR();
            ldb2(b0, 2);
            BAR();
            MFMA_QUAD(0, 2);
            BAR();
            lda4(a0, 4);
            if (st) stage(Bb, (char*)Bs, u2, 0);
            BAR();
            MFMA_QUAD(4, 0);
            BAR();
            if (st) stage(Bb, (char*)Bs, u2, 1);
            BAR();
            MFMA_QUAD(4, 2);
            if (it == 0) { WAIT_VM36(); }                  // bufs landed at boundary;
            else if (st) { WAIT_VM4(); }                   // let C-stores drain in bg
            else { WAIT_VM0(); }
            BAR();

            // ===== tile v (buf1), phases 5-8 =====
            lda4(a1, 0); ldb2(b1, 0);
            if (st) stage(Ab, (char*)As, u2, 0);
            BAR();
            MFMA_QUAD(0, 0);
            BAR();
            ldb2(b1, 2);
            if (st) stage(Ab, (char*)As, u2, 1);
            BAR();
            MFMA_QUAD(0, 2);
            BAR();
            lda4(a1, 4);
            if (st) stage(Bb, (char*)Bs, v2, 0);
            BAR();
            MFMA_QUAD(4, 0);
            BAR();
            if (st) { stage(Bb, (char*)Bs, v2, 1); stage(Ab, (char*)As, v2, 0); stage(Ab, (char*)As, v2, 1); }
            BAR();
            MFMA_QUAD(4, 2);
            if (st) { WAIT_VM8(); } else { WAIT_VM0(); }   // next buf0 landed
            BAR();
        }

        // boundary: prologue loads FIRST (oldest in vmcnt order), then stores
        bool more = (i + 1 < cnt);
        if (more) {
            int t1 = t0 + 256;
            int rp1 = t1 % mtiles, cp1 = t1 / mtiles;
            prolog(A + (size_t)rp1 * 256 * K, Bt + (size_t)cp1 * 256 * K);
        }
        int crow = rp * 256 + wr * 128 + hi * 4;
        int ccol = cp * 256 + wc * 64 + lr;
#pragma unroll
        for (int m = 0; m < 8; ++m)
#pragma unroll
            for (int n = 0; n < 4; ++n) {
#pragma unroll
                for (int j = 0; j < 4; ++j)
                    C[(size_t)(crow + m * 16 + j) * N + ccol + n * 16] = acc[m][n][j];
            }
        if (more) {
            WAIT_VM32();   // 16 prologue loads retired; stores drain in bg
            BAR();
        }
    }
#undef MFMA_QUAD
}

// ---------------- flash attention ----------------
__global__ __launch_bounds__(256) void k_attn(const short* __restrict__ q,
                                              const short* __restrict__ k,
                                              const short* __restrict__ vT,
                                              short* __restrict__ out) {
    int qt = blockIdx.x, head = blockIdx.y, b = blockIdx.z;
    int qbase = qt * 64;
    __shared__ short Qs[64][72];
    __shared__ short Ps[4][16][72];
    int tid = threadIdx.x, lane = tid & 63, w = tid >> 6;
    int lr = lane & 15, lg4 = (lane >> 4) * 4, lk8 = (lane >> 4) * 8;

#pragma unroll
    for (int c = 0; c < 2; ++c) {
        int chunk = tid + 256 * c;
        int row = chunk >> 3, h8 = (chunk & 7) * 8;
        *(short8*)&Qs[row][h8] =
            *(const short8*)&q[(size_t)(b * T_ + qbase + row) * H_ + head * HD_ + h8];
    }
    __syncthreads();

    short8 qf[2];
    qf[0] = *(short8*)&Qs[w * 16 + lr][lk8];
    qf[1] = *(short8*)&Qs[w * 16 + lr][32 + lk8];

    f32x4 o[4] = {};
    float lsum[4] = {0.f, 0.f, 0.f, 0.f};

    for (int kt = 0; kt <= qt; ++kt) {
        int kb = kt * 64;
        f32x4 s[4] = {};
#pragma unroll
        for (int ks = 0; ks < 2; ++ks) {
#pragma unroll
            for (int f = 0; f < 4; ++f) {
                short8 kf = *(const short8*)&k[(size_t)(b * T_ + kb + f * 16 + lr) * H_ +
                                               head * HD_ + ks * 32 + lk8];
                s[f] = __builtin_amdgcn_mfma_f32_16x16x32_bf16(qf[ks], kf, s[f], 0, 0, 0);
            }
        }
        if (kt == qt) {
#pragma unroll
            for (int f = 0; f < 4; ++f) {
                int key = kb + f * 16 + lr;
#pragma unroll
                for (int j = 0; j < 4; ++j) {
                    int qrow = qbase + w * 16 + lg4 + j;
                    if (key > qrow) s[f][j] = -1e30f;
                }
            }
        }
#pragma unroll
        for (int j = 0; j < 4; ++j) {
#pragma unroll
            for (int f = 0; f < 4; ++f) {
                float p = __expf(fminf(s[f][j], 60.f));
                s[f][j] = p;
                lsum[j] += p;
            }
#pragma unroll
            for (int f = 0; f < 4; ++f) Ps[w][lg4 + j][f * 16 + lr] = f2bf(s[f][j]);
        }
#pragma unroll
        for (int ks2 = 0; ks2 < 2; ++ks2) {
            short8 pf = *(short8*)&Ps[w][lr][ks2 * 32 + lk8];
            __builtin_amdgcn_s_setprio(1);
#pragma unroll
            for (int f = 0; f < 4; ++f) {
                short8 vf = *(const short8*)&vT[((size_t)(b * HEADS_ + head) * HD_ + f * 16 + lr) * T_ +
                                                kb + ks2 * 32 + lk8];
                o[f] = __builtin_amdgcn_mfma_f32_16x16x32_bf16(pf, vf, o[f], 0, 0, 0);
            }
            __builtin_amdgcn_s_setprio(0);
        }
    }
#pragma unroll
    for (int j = 0; j < 4; ++j) {
#pragma unroll
        for (int off = 1; off < 16; off <<= 1) lsum[j] += __shfl_xor(lsum[j], off, 64);
    }
#pragma unroll
    for (int f = 0; f < 4; ++f)
#pragma unroll
        for (int j = 0; j < 4; ++j) {
            float val = o[f][j] / lsum[j];
            out[(size_t)(b * T_ + qbase + w * 16 + lg4 + j) * H_ + head * HD_ + f * 16 + lr] =
                f2bf(val);
        }
}

// ---------------- launch ----------------
extern "C" void kernel_launch(void* const* d_in, const int* in_sizes, int n_in,
                              void* d_out, int out_size, void* d_ws, size_t ws_size,
                              hipStream_t stream) {
    const float* prefix = (const float*)d_in[0];
    const int* ids = (const int*)d_in[1];
    const float* emb = (const float*)d_in[2];
    const float* Wq = (const float*)d_in[3];
    const float* Wk = (const float*)d_in[4];
    const float* Wv = (const float*)d_in[5];
    const float* Wo = (const float*)d_in[6];
    const float* g1 = (const float*)d_in[7];
    const float* b1 = (const float*)d_in[8];
    const float* g2 = (const float*)d_in[9];
    const float* b2 = (const float*)d_in[10];
    const float* W1 = (const float*)d_in[11];
    const float* bm1 = (const float*)d_in[12];
    const float* W2 = (const float*)d_in[13];
    const float* bm2 = (const float*)d_in[14];
    const float* gf = (const float*)d_in[15];
    const float* bf = (const float*)d_in[16];
    const float* Whead = (const float*)d_in[17];
    float* out = (float*)d_out;

    char* wsp = (char*)d_ws;
    float* x = (float*)wsp;   wsp += (size_t)BT_ * H_ * 4;
    short* p = (short*)wsp;   wsp += (size_t)4 * BT_ * H_ * 2;   // bf16 split-K slabs
    short* h = (short*)wsp;   wsp += (size_t)BT_ * H_ * 2;
    short* qb = (short*)wsp;  wsp += (size_t)BT_ * H_ * 2;
    short* kb = (short*)wsp;  wsp += (size_t)BT_ * H_ * 2;
    short* vT = (short*)wsp;  wsp += (size_t)BT_ * H_ * 2;
    short* ao = (short*)wsp;  wsp += (size_t)BT_ * H_ * 2;
    short* mid = (short*)wsp; wsp += (size_t)BT_ * F_ * 2;
    short* WqkvT = (short*)wsp; wsp += (size_t)NL_ * 3 * H_ * H_ * 2;
    short* WoT = (short*)wsp;   wsp += (size_t)NL_ * H_ * H_ * 2;
    short* W1T = (short*)wsp;   wsp += (size_t)NL_ * H_ * F_ * 2;
    short* W2T = (short*)wsp;   wsp += (size_t)NL_ * F_ * H_ * 2;
    short* WhT = (short*)wsp;   wsp += (size_t)H_ * V_ * 2;

    dim3 blk(256);
    k_cvt_all<<<dim3(14144), blk, 0, stream>>>(Wq, Wk, Wv, Wo, W1, W2, Whead,
                                               WqkvT, WoT, W1T, W2T, WhT);
    k_embed_ln<<<BT_, blk, 0, stream>>>(prefix, ids, emb, g1, b1, x, h);
    for (int l = 0; l < NL_; ++l) {
        size_t o1 = (size_t)l * H_ * H_;
        size_t oq = (size_t)l * 3 * H_ * H_;
        size_t o2 = (size_t)l * H_ * F_;
        k_gemm<3, false, false, 1><<<dim3(576), blk, 0, stream>>>(
            h, WqkvT + oq, nullptr, qb, kb, vT, BT_, 3 * H_, H_, 1.f);
        k_attn<<<dim3(T_ / 64, HEADS_, B_), blk, 0, stream>>>(qb, kb, vT, ao);
        k_gemm<0, false, false, 4><<<dim3(768), blk, 0, stream>>>(
            ao, WoT + o1, nullptr, p, nullptr, nullptr, BT_, H_, H_, 1.f);
        k_add_ln<<<BT_, blk, 0, stream>>>(x, p, g2 + l * H_, b2 + l * H_, h);
        k_gemm<1, true, true, 1><<<dim3(768), blk, 0, stream>>>(
            h, W1T + o2, bm1 + (size_t)l * F_, mid, nullptr, nullptr, BT_, F_, H_, 1.f);
        k_gemm<0, true, false, 4><<<dim3(768), blk, 0, stream>>>(
            mid, W2T + o2, bm2 + (size_t)l * H_, p, nullptr, nullptr, BT_, H_, F_, 1.f);
        const float* gn = (l + 1 < NL_) ? g1 + (l + 1) * H_ : gf;
        const float* bn = (l + 1 < NL_) ? b1 + (l + 1) * H_ : bf;
        k_add_ln<<<BT_, blk, 0, stream>>>(x, p, gn, bn, h);
    }
    // head GEMM: persistent 8-phase kernel, grid MUST be 256 (stride walk)
    k_gemm8<<<dim3(256), dim3(512), 0, stream>>>(h, WhT, out, BT_, V_, H_);
}

// Round 21
// 781.661 us; speedup vs baseline: 1.0303x; 1.0303x over previous
//
#include <hip/hip_runtime.h>
#include <stdint.h>

#define B_ 2
#define P_ 256
#define TL_ 1280
#define T_ 1536
#define H_ 1024
#define HEADS_ 16
#define HD_ 64
#define NL_ 2
#define V_ 32000
#define F_ 4096
#define BT_ (B_ * T_)

typedef __attribute__((ext_vector_type(4))) float f32x4;
typedef __attribute__((ext_vector_type(8))) short short8;
typedef __attribute__((ext_vector_type(4))) short short4v;

typedef __attribute__((address_space(3))) uint32_t lds_u32_t;
typedef const __attribute__((address_space(1))) uint32_t glb_u32_t;

__device__ inline void gload_lds16(const void* g, void* l) {
    __builtin_amdgcn_global_load_lds((glb_u32_t*)g, (lds_u32_t*)l, 16, 0, 0);
}

__device__ inline short f2bf(float f) {
    union { float f; unsigned u; } v; v.f = f;
    unsigned r = v.u + 0x7FFF + ((v.u >> 16) & 1);
    return (short)(r >> 16);
}

__device__ inline float bf2f(short s) {
    union { unsigned u; float f; } v;
    v.u = ((unsigned)(unsigned short)s) << 16;
    return v.f;
}

#define BAR() asm volatile("s_barrier" ::: "memory")
#define WAIT_VM0() asm volatile("s_waitcnt vmcnt(0)" ::: "memory")
#define WAIT_VM4() asm volatile("s_waitcnt vmcnt(4)" ::: "memory")
#define WAIT_VM8() asm volatile("s_waitcnt vmcnt(8)" ::: "memory")
#define WAIT_VM32() asm volatile("s_waitcnt vmcnt(32)" ::: "memory")
#define WAIT_VM36() asm volatile("s_waitcnt vmcnt(36)" ::: "memory")

// ---------------- fused weight transpose-convert: f32 [K,N] -> bf16 [N,K] ----
__global__ __launch_bounds__(256) void k_cvt_all(
    const float* __restrict__ Wq, const float* __restrict__ Wk,
    const float* __restrict__ Wv, const float* __restrict__ Wo,
    const float* __restrict__ W1, const float* __restrict__ W2,
    const float* __restrict__ Wh,
    short* __restrict__ WqkvT, short* __restrict__ WoT,
    short* __restrict__ W1T, short* __restrict__ W2T, short* __restrict__ WhT) {
    int id = blockIdx.x;
    const float* src;
    short* dst;
    int K, N;
    float scale = 1.f;
    if (id < 1536) {                       // qkv: 6 mats x 256 tiles
        int mat = id >> 8;
        int tile = id & 255;
        int l = mat / 3, which = mat - l * 3;
        src = (which == 0 ? Wq : which == 1 ? Wk : Wv) + (size_t)l * H_ * H_;
        dst = WqkvT + (size_t)(l * 3 + which) * H_ * H_;
        K = H_; N = H_;
        if (which == 0) scale = 0.125f;
        id = tile;
    } else if (id < 2048) {                // wo: 2 x 256
        int rel = id - 1536;
        int l = rel >> 8;
        src = Wo + (size_t)l * H_ * H_;
        dst = WoT + (size_t)l * H_ * H_;
        K = H_; N = H_;
        id = rel & 255;
    } else if (id < 4096) {                // w1: 2 x 1024
        int rel = id - 2048;
        int l = rel >> 10;
        src = W1 + (size_t)l * H_ * F_;
        dst = W1T + (size_t)l * H_ * F_;
        K = H_; N = F_;
        id = rel & 1023;
    } else if (id < 6144) {                // w2: 2 x 1024
        int rel = id - 4096;
        int l = rel >> 10;
        src = W2 + (size_t)l * F_ * H_;
        dst = W2T + (size_t)l * F_ * H_;
        K = F_; N = H_;
        id = rel & 1023;
    } else {                               // head: 8000 tiles
        id -= 6144;
        src = Wh; dst = WhT;
        K = H_; N = V_;
    }
    int ntn = N >> 6;
    int nb = (id % ntn) * 64, kb = (id / ntn) * 64;

    __shared__ float ts[64][65];
    int tid = threadIdx.x;
    int rr = tid >> 4, c4 = (tid & 15) * 4;
#pragma unroll
    for (int it = 0; it < 4; ++it) {
        int r = rr + it * 16;
        f32x4 v = __builtin_nontemporal_load(
            (const f32x4*)&src[(size_t)(kb + r) * N + nb + c4]);
        *(f32x4*)&ts[r][c4] = v;
    }
    __syncthreads();
    int wn = tid >> 2, ko = (tid & 3) * 16;
    short o[16];
#pragma unroll
    for (int j = 0; j < 16; ++j) o[j] = f2bf(ts[ko + j][wn] * scale);
    short* dp = &dst[(size_t)(nb + wn) * K + kb + ko];
    *(short8*)&dp[0] = *(short8*)&o[0];
    *(short8*)&dp[8] = *(short8*)&o[8];
}

// ---------------- embed + concat + first layernorm ---------------------------
__global__ __launch_bounds__(256) void k_embed_ln(const float* __restrict__ prefix,
                                                  const int* __restrict__ ids,
                                                  const float* __restrict__ emb,
                                                  const float* __restrict__ g,
                                                  const float* __restrict__ b,
                                                  float* __restrict__ x,
                                                  short* __restrict__ h) {
    int r = blockIdx.x;
    int bb = r / T_, t = r % T_;
    const float* src = (t < P_) ? (prefix + (size_t)(bb * P_ + t) * H_)
                                : (emb + (size_t)ids[bb * TL_ + (t - P_)] * H_);
    int tid = threadIdx.x;
    f32x4 v = *(const f32x4*)&src[tid * 4];
    *(f32x4*)&x[(size_t)r * H_ + tid * 4] = v;
    float s = v[0] + v[1] + v[2] + v[3];
    float sq = v[0] * v[0] + v[1] * v[1] + v[2] * v[2] + v[3] * v[3];
#pragma unroll
    for (int off = 32; off; off >>= 1) {
        s += __shfl_down(s, off, 64);
        sq += __shfl_down(sq, off, 64);
    }
    __shared__ float red[10];
    int wid = tid >> 6;
    if ((tid & 63) == 0) { red[wid] = s; red[4 + wid] = sq; }
    __syncthreads();
    if (tid == 0) {
        float S = red[0] + red[1] + red[2] + red[3];
        float SQ = red[4] + red[5] + red[6] + red[7];
        float mu = S * (1.0f / H_);
        float var = SQ * (1.0f / H_) - mu * mu;
        red[8] = mu;
        red[9] = rsqrtf(var + 1e-5f);
    }
    __syncthreads();
    float mu = red[8], rstd = red[9];
    short o[4];
#pragma unroll
    for (int j = 0; j < 4; ++j)
        o[j] = f2bf((v[j] - mu) * rstd * g[tid * 4 + j] + b[tid * 4 + j]);
    *(short4v*)&h[(size_t)r * H_ + tid * 4] = *(short4v*)o;
}

// -------- x += p0+p1+p2+p3 (bf16 split-K slabs), then LN -> bf16 -------------
__global__ __launch_bounds__(256) void k_add_ln(float* __restrict__ x,
                                                const short* __restrict__ p,
                                                const float* __restrict__ g,
                                                const float* __restrict__ b,
                                                short* __restrict__ out) {
    int r = blockIdx.x;
    int tid = threadIdx.x;
    size_t base = (size_t)r * H_ + tid * 4;
    f32x4 v = *(f32x4*)&x[base];
#pragma unroll
    for (int sl = 0; sl < 4; ++sl) {
        short4v a = *(const short4v*)&p[(size_t)sl * BT_ * H_ + base];
#pragma unroll
        for (int j = 0; j < 4; ++j) v[j] += bf2f(a[j]);
    }
    *(f32x4*)&x[base] = v;
    float s = v[0] + v[1] + v[2] + v[3];
    float sq = v[0] * v[0] + v[1] * v[1] + v[2] * v[2] + v[3] * v[3];
#pragma unroll
    for (int off = 32; off; off >>= 1) {
        s += __shfl_down(s, off, 64);
        sq += __shfl_down(sq, off, 64);
    }
    __shared__ float red[10];
    int wid = tid >> 6;
    if ((tid & 63) == 0) { red[wid] = s; red[4 + wid] = sq; }
    __syncthreads();
    if (tid == 0) {
        float S = red[0] + red[1] + red[2] + red[3];
        float SQ = red[4] + red[5] + red[6] + red[7];
        float mu = S * (1.0f / H_);
        float var = SQ * (1.0f / H_) - mu * mu;
        red[8] = mu;
        red[9] = rsqrtf(var + 1e-5f);
    }
    __syncthreads();
    float mu = red[8], rstd = red[9];
    short o[4];
#pragma unroll
    for (int j = 0; j < 4; ++j)
        o[j] = f2bf((v[j] - mu) * rstd * g[tid * 4 + j] + b[tid * 4 + j]);
    *(short4v*)&out[base] = *(short4v*)o;
}

// ---------------- 128x128 GEMM, BK=64, DOUBLE-buffered -----------------------
// STORE: 0 = bf16 split-K partial slab, 1 = bf16 (+bias+silu), 3 = fused QKV
template <int STORE, bool HAS_BIAS, bool SILU, int NSPLIT>
__global__ __launch_bounds__(256) void k_gemm(const short* __restrict__ A,
                                              const short* __restrict__ Bt,
                                              const float* __restrict__ bias,
                                              void* __restrict__ outp,
                                              void* __restrict__ outp2,
                                              void* __restrict__ outp3,
                                              int M, int N, int K, float alpha) {
    __shared__ short SH[32768];   // 64 KiB
    int tid = threadIdx.x;
    int lane = tid & 63, w = tid >> 6;
    int wr = w >> 1, wc = w & 1;
    int nwg = gridDim.x;
    int mblocks = M >> 7;
    int cpx = nwg >> 3;
    int logical = (blockIdx.x & 7) * cpx + (blockIdx.x >> 3);
    int ks = 0;
    if (NSPLIT > 1) {
        int per = mblocks * (N >> 7);
        ks = logical / per;
        logical -= ks * per;
    }
    int rp = logical % mblocks, cp = logical / mblocks;
    int mbase = rp * 128, nbase = cp * 128;
    int Kh = K / NSPLIT;
    int lr = lane & 15, hi = lane >> 4;
    int lg = hi * 4;

    f32x4 acc[4][4] = {};

    const short* Ab = A + (size_t)mbase * K + (size_t)ks * Kh;
    const short* Bb = Bt + (size_t)nbase * K + (size_t)ks * Kh;

    int koffb[2];
    koffb[0] = ((hi) ^ (lr & 7)) << 4;
    koffb[1] = ((4 + hi) ^ (lr & 7)) << 4;
    int arowb[4], browb[4];
#pragma unroll
    for (int m = 0; m < 4; ++m) arowb[m] = (wr * 64 + m * 16 + lr) * 128;
#pragma unroll
    for (int n = 0; n < 4; ++n) browb[n] = (wc * 64 + n * 16 + lr) * 128;

    auto stage = [&](int t, int buf) {
        short* la = SH + buf * 8192;
        short* lb = SH + 16384 + buf * 8192;
#pragma unroll
        for (int c = 0; c < 4; ++c) {
            int S = tid + 256 * c;
            int r = S >> 3, ch = S & 7;
            int gofs = t * 64 + ((ch ^ (r & 7)) << 3);
            gload_lds16(Ab + (size_t)r * K + gofs, la + S * 8);
            gload_lds16(Bb + (size_t)r * K + gofs, lb + S * 8);
        }
    };

    int NT = Kh >> 6;
    stage(0, 0);
    WAIT_VM0();
    BAR();

    for (int t = 0; t < NT; ++t) {
        if (t + 1 < NT) stage(t + 1, (t + 1) & 1);
        const char* a = (const char*)(SH + (t & 1) * 8192);
        const char* b = (const char*)(SH + 16384 + (t & 1) * 8192);
        short8 af[2][4], bfr[2][4];
#pragma unroll
        for (int kk = 0; kk < 2; ++kk) {
#pragma unroll
            for (int m = 0; m < 4; ++m) af[kk][m] = *(const short8*)(a + arowb[m] + koffb[kk]);
#pragma unroll
            for (int n = 0; n < 4; ++n) bfr[kk][n] = *(const short8*)(b + browb[n] + koffb[kk]);
        }
        __builtin_amdgcn_s_setprio(1);
#pragma unroll
        for (int kk = 0; kk < 2; ++kk)
#pragma unroll
            for (int m = 0; m < 4; ++m)
#pragma unroll
                for (int n = 0; n < 4; ++n)
                    acc[m][n] = __builtin_amdgcn_mfma_f32_16x16x32_bf16(af[kk][m], bfr[kk][n], acc[m][n], 0, 0, 0);
        __builtin_amdgcn_s_setprio(0);
        if (t + 1 < NT) {
            WAIT_VM0();
            BAR();
        }
    }

    if (STORE == 3 && nbase >= 2048) {
        BAR();
        short* Tt = SH;
#pragma unroll
        for (int ni = 0; ni < 4; ++ni) {
            int c2 = wc * 64 + ni * 16 + lr;
#pragma unroll
            for (int mi = 0; mi < 4; ++mi)
#pragma unroll
                for (int j = 0; j < 4; ++j)
                    Tt[c2 * 136 + wr * 64 + mi * 16 + lg + j] = f2bf(acc[mi][ni][j]);
        }
        BAR();
        int c2 = tid >> 1;
        int half = (tid & 1) * 64;
        int cc = (nbase + c2) & 1023;
        int head = cc >> 6, hd = cc & 63;
        int bb = mbase / T_;
        int t0 = mbase - bb * T_;
        short* dst = (short*)outp3 +
                     ((size_t)(bb * HEADS_ + head) * HD_ + hd) * T_ + t0 + half;
#pragma unroll
        for (int r8 = 0; r8 < 8; ++r8)
            *(short8*)&dst[r8 * 8] = *(short8*)&Tt[c2 * 136 + half + r8 * 8];
        return;
    }

#pragma unroll
    for (int ni = 0; ni < 4; ++ni) {
        int col = nbase + wc * 64 + ni * 16 + lr;
        float bv = (HAS_BIAS && ks == 0) ? bias[col] : 0.f;
#pragma unroll
        for (int mi = 0; mi < 4; ++mi) {
#pragma unroll
            for (int j = 0; j < 4; ++j) {
                int row = mbase + wr * 64 + mi * 16 + lg + j;
                float vv = acc[mi][ni][j] * alpha + bv;
                if (SILU) vv = vv / (1.f + __expf(-vv));
                if (STORE == 0) {
                    ((short*)outp)[(size_t)ks * M * N + (size_t)row * N + col] = f2bf(vv);
                } else if (STORE == 1) {
                    ((short*)outp)[(size_t)row * N + col] = f2bf(vv);
                } else {
                    int seg = col >> 10;
                    int c = col & 1023;
                    if (seg == 0) {
                        ((short*)outp)[(size_t)row * H_ + c] = f2bf(vv);
                    } else {
                        ((short*)outp2)[(size_t)row * H_ + c] = f2bf(vv);
                    }
                }
            }
        }
    }
}

// ---------------- 8-phase 256x256 GEMM, PERSISTENT (grid 256) ----------------
// r21: CHUNKED tile walk restored (r18/r19 verified, 226 us).  The r20
// stride-256 walk cut FETCH 245->208 MB but REGRESSED time (244-249 us):
// chunked's asset is temporal reuse WITHIN a block (same B-panel for 12
// consecutive tiles -> 11/12 warm prologues); strided made every boundary a
// cold panel fetch on the critical path.  Both cache-layout theories are now
// refuted at matched conditions; chunked accepted as local optimum.
// r18 slack waits + boundary prolog-before-stores unchanged.
// DO NOT cap registers below 256/wave (r3: spills, 7.5x slow).
__global__ __launch_bounds__(512, 2) void k_gemm8(const short* __restrict__ A,
                                                  const short* __restrict__ Bt,
                                                  float* __restrict__ C,
                                                  int M, int N, int K) {
    __shared__ short As[2 * 256 * 64];   // 64 KiB
    __shared__ short Bs[2 * 256 * 64];   // 64 KiB
    int tid = threadIdx.x;
    int lane = tid & 63, w = tid >> 6;
    int wr = w >> 2, wc = w & 3;
    int lr = lane & 15, hi = lane >> 4;

    int mtiles = M >> 8;
    int total = mtiles * (N >> 8);
    int g = ((blockIdx.x & 7) << 5) + (blockIdx.x >> 3);
    int qq = total >> 8, rr = total & 255;
    int start = g * qq + (g < rr ? g : rr);
    int cnt = qq + (g < rr ? 1 : 0);

    int r0 = tid >> 3;
    int gcol = ((tid & 7) ^ (r0 & 7)) * 8;
    int koff0 = (hi * 16) ^ ((lr & 7) << 4);
    int koff1 = (64 + hi * 16) ^ ((lr & 7) << 4);
    int arow[8], brow[4];
#pragma unroll
    for (int m = 0; m < 8; ++m) arow[m] = (wr * 128 + m * 16 + lr) * 128;
#pragma unroll
    for (int n = 0; n < 4; ++n) brow[n] = (wc * 64 + n * 16 + lr) * 128;

    f32x4 acc[8][4];
    short8 aF[4][2], bF[4][2];
    const char* Ac = (const char*)As;
    const char* Bc = (const char*)Bs;

    auto stage = [&](const short* Gb, char* Lb, int tau, int hf) {
        const short* g0 = Gb + (size_t)(hf * 128 + r0) * K + tau * 64 + gcol;
        char* l = Lb + (tau & 1) * 32768 + hf * 16384;
        gload_lds16(g0, l + tid * 16);
        gload_lds16(g0 + (size_t)64 * K, l + (tid + 512) * 16);
    };
    auto prolog = [&](const short* Ab, const short* Bb) {
        stage(Ab, (char*)As, 0, 0); stage(Ab, (char*)As, 0, 1);
        stage(Bb, (char*)Bs, 0, 0); stage(Bb, (char*)Bs, 0, 1);
        stage(Ab, (char*)As, 1, 0); stage(Ab, (char*)As, 1, 1);
        stage(Bb, (char*)Bs, 1, 0); stage(Bb, (char*)Bs, 1, 1);
    };
    auto lda4 = [&](const char* base, int roff) {
#pragma unroll
        for (int m = 0; m < 4; ++m) {
            aF[m][0] = *(const short8*)(base + arow[roff + m] + koff0);
            aF[m][1] = *(const short8*)(base + arow[roff + m] + koff1);
        }
    };
    auto ldb2 = [&](const char* base, int noff) {
#pragma unroll
        for (int n = 0; n < 2; ++n) {
            bF[noff + n][0] = *(const short8*)(base + brow[noff + n] + koff0);
            bF[noff + n][1] = *(const short8*)(base + brow[noff + n] + koff1);
        }
    };

#define MFMA_QUAD(MOFF, NOFF)                                                          \
    __builtin_amdgcn_s_setprio(1);                                                     \
    _Pragma("unroll") for (int m = 0; m < 4; ++m) {                                    \
        _Pragma("unroll") for (int n = 0; n < 2; ++n) {                                \
            acc[MOFF + m][NOFF + n] = __builtin_amdgcn_mfma_f32_16x16x32_bf16(         \
                aF[m][0], bF[NOFF + n][0], acc[MOFF + m][NOFF + n], 0, 0, 0);          \
            acc[MOFF + m][NOFF + n] = __builtin_amdgcn_mfma_f32_16x16x32_bf16(         \
                aF[m][1], bF[NOFF + n][1], acc[MOFF + m][NOFF + n], 0, 0, 0);          \
        }                                                                              \
    }                                                                                  \
    __builtin_amdgcn_s_setprio(0);

    int NK = K >> 6;
    int niters = NK >> 1;

    for (int i = 0; i < cnt; ++i) {
        int t0 = start + i;
        int rp = t0 % mtiles, cp = t0 / mtiles;
        const short* Ab = A + (size_t)rp * 256 * K;
        const short* Bb = Bt + (size_t)cp * 256 * K;
        f32x4 zz = {0.f, 0.f, 0.f, 0.f};
#pragma unroll
        for (int m = 0; m < 8; ++m)
#pragma unroll
            for (int n = 0; n < 4; ++n) acc[m][n] = zz;

        if (i == 0) {
            prolog(Ab, Bb);
            WAIT_VM0();
            BAR();
        }

        for (int it = 0; it < niters; ++it) {
            bool st = it < niters - 1;
            int u2 = 2 * it + 2, v2 = 2 * it + 3;
            const char* a0 = Ac;            const char* b0 = Bc;
            const char* a1 = Ac + 32768;    const char* b1 = Bc + 32768;

            // ===== tile u (buf0), phases 1-4 =====
            lda4(a0, 0); ldb2(b0, 0);
            BAR();
            MFMA_QUAD(0, 0);
            BAR();
            ldb2(b0, 2);
            BAR();
            MFMA_QUAD(0, 2);
            BAR();
            lda4(a0, 4);
            if (st) stage(Bb, (char*)Bs, u2, 0);
            BAR();
            MFMA_QUAD(4, 0);
            BAR();
            if (st) stage(Bb, (char*)Bs, u2, 1);
            BAR();
            MFMA_QUAD(4, 2);
            if (it == 0) { WAIT_VM36(); }                  // bufs landed at boundary;
            else if (st) { WAIT_VM4(); }                   // let C-stores drain in bg
            else { WAIT_VM0(); }
            BAR();

            // ===== tile v (buf1), phases 5-8 =====
            lda4(a1, 0); ldb2(b1, 0);
            if (st) stage(Ab, (char*)As, u2, 0);
            BAR();
            MFMA_QUAD(0, 0);
            BAR();
            ldb2(b1, 2);
            if (st) stage(Ab, (char*)As, u2, 1);
            BAR();
            MFMA_QUAD(0, 2);
            BAR();
            lda4(a1, 4);
            if (st) stage(Bb, (char*)Bs, v2, 0);
            BAR();
            MFMA_QUAD(4, 0);
            BAR();
            if (st) { stage(Bb, (char*)Bs, v2, 1); stage(Ab, (char*)As, v2, 0); stage(Ab, (char*)As, v2, 1); }
            BAR();
            MFMA_QUAD(4, 2);
            if (st) { WAIT_VM8(); } else { WAIT_VM0(); }   // next buf0 landed
            BAR();
        }

        // boundary: prologue loads FIRST (oldest in vmcnt order), then stores
        bool more = (i + 1 < cnt);
        if (more) {
            int t1 = t0 + 1;
            int rp1 = t1 % mtiles, cp1 = t1 / mtiles;
            prolog(A + (size_t)rp1 * 256 * K, Bt + (size_t)cp1 * 256 * K);
        }
        int crow = rp * 256 + wr * 128 + hi * 4;
        int ccol = cp * 256 + wc * 64 + lr;
#pragma unroll
        for (int m = 0; m < 8; ++m)
#pragma unroll
            for (int n = 0; n < 4; ++n) {
#pragma unroll
                for (int j = 0; j < 4; ++j)
                    C[(size_t)(crow + m * 16 + j) * N + ccol + n * 16] = acc[m][n][j];
            }
        if (more) {
            WAIT_VM32();   // 16 prologue loads retired; stores drain in bg
            BAR();
        }
    }
#undef MFMA_QUAD
}

// ---------------- flash attention ----------------
__global__ __launch_bounds__(256) void k_attn(const short* __restrict__ q,
                                              const short* __restrict__ k,
                                              const short* __restrict__ vT,
                                              short* __restrict__ out) {
    int qt = blockIdx.x, head = blockIdx.y, b = blockIdx.z;
    int qbase = qt * 64;
    __shared__ short Qs[64][72];
    __shared__ short Ps[4][16][72];
    int tid = threadIdx.x, lane = tid & 63, w = tid >> 6;
    int lr = lane & 15, lg4 = (lane >> 4) * 4, lk8 = (lane >> 4) * 8;

#pragma unroll
    for (int c = 0; c < 2; ++c) {
        int chunk = tid + 256 * c;
        int row = chunk >> 3, h8 = (chunk & 7) * 8;
        *(short8*)&Qs[row][h8] =
            *(const short8*)&q[(size_t)(b * T_ + qbase + row) * H_ + head * HD_ + h8];
    }
    __syncthreads();

    short8 qf[2];
    qf[0] = *(short8*)&Qs[w * 16 + lr][lk8];
    qf[1] = *(short8*)&Qs[w * 16 + lr][32 + lk8];

    f32x4 o[4] = {};
    float lsum[4] = {0.f, 0.f, 0.f, 0.f};

    for (int kt = 0; kt <= qt; ++kt) {
        int kb = kt * 64;
        f32x4 s[4] = {};
#pragma unroll
        for (int ks = 0; ks < 2; ++ks) {
#pragma unroll
            for (int f = 0; f < 4; ++f) {
                short8 kf = *(const short8*)&k[(size_t)(b * T_ + kb + f * 16 + lr) * H_ +
                                               head * HD_ + ks * 32 + lk8];
                s[f] = __builtin_amdgcn_mfma_f32_16x16x32_bf16(qf[ks], kf, s[f], 0, 0, 0);
            }
        }
        if (kt == qt) {
#pragma unroll
            for (int f = 0; f < 4; ++f) {
                int key = kb + f * 16 + lr;
#pragma unroll
                for (int j = 0; j < 4; ++j) {
                    int qrow = qbase + w * 16 + lg4 + j;
                    if (key > qrow) s[f][j] = -1e30f;
                }
            }
        }
#pragma unroll
        for (int j = 0; j < 4; ++j) {
#pragma unroll
            for (int f = 0; f < 4; ++f) {
                float p = __expf(fminf(s[f][j], 60.f));
                s[f][j] = p;
                lsum[j] += p;
            }
#pragma unroll
            for (int f = 0; f < 4; ++f) Ps[w][lg4 + j][f * 16 + lr] = f2bf(s[f][j]);
        }
#pragma unroll
        for (int ks2 = 0; ks2 < 2; ++ks2) {
            short8 pf = *(short8*)&Ps[w][lr][ks2 * 32 + lk8];
            __builtin_amdgcn_s_setprio(1);
#pragma unroll
            for (int f = 0; f < 4; ++f) {
                short8 vf = *(const short8*)&vT[((size_t)(b * HEADS_ + head) * HD_ + f * 16 + lr) * T_ +
                                                kb + ks2 * 32 + lk8];
                o[f] = __builtin_amdgcn_mfma_f32_16x16x32_bf16(pf, vf, o[f], 0, 0, 0);
            }
            __builtin_amdgcn_s_setprio(0);
        }
    }
#pragma unroll
    for (int j = 0; j < 4; ++j) {
#pragma unroll
        for (int off = 1; off < 16; off <<= 1) lsum[j] += __shfl_xor(lsum[j], off, 64);
    }
#pragma unroll
    for (int f = 0; f < 4; ++f)
#pragma unroll
        for (int j = 0; j < 4; ++j) {
            float val = o[f][j] / lsum[j];
            out[(size_t)(b * T_ + qbase + w * 16 + lg4 + j) * H_ + head * HD_ + f * 16 + lr] =
                f2bf(val);
        }
}

// ---------------- launch ----------------
extern "C" void kernel_launch(void* const* d_in, const int* in_sizes, int n_in,
                              void* d_out, int out_size, void* d_ws, size_t ws_size,
                              hipStream_t stream) {
    const float* prefix = (const float*)d_in[0];
    const int* ids = (const int*)d_in[1];
    const float* emb = (const float*)d_in[2];
    const float* Wq = (const float*)d_in[3];
    const float* Wk = (const float*)d_in[4];
    const float* Wv = (const float*)d_in[5];
    const float* Wo = (const float*)d_in[6];
    const float* g1 = (const float*)d_in[7];
    const float* b1 = (const float*)d_in[8];
    const float* g2 = (const float*)d_in[9];
    const float* b2 = (const float*)d_in[10];
    const float* W1 = (const float*)d_in[11];
    const float* bm1 = (const float*)d_in[12];
    const float* W2 = (const float*)d_in[13];
    const float* bm2 = (const float*)d_in[14];
    const float* gf = (const float*)d_in[15];
    const float* bf = (const float*)d_in[16];
    const float* Whead = (const float*)d_in[17];
    float* out = (float*)d_out;

    char* wsp = (char*)d_ws;
    float* x = (float*)wsp;   wsp += (size_t)BT_ * H_ * 4;
    short* p = (short*)wsp;   wsp += (size_t)4 * BT_ * H_ * 2;   // bf16 split-K slabs
    short* h = (short*)wsp;   wsp += (size_t)BT_ * H_ * 2;
    short* qb = (short*)wsp;  wsp += (size_t)BT_ * H_ * 2;
    short* kb = (short*)wsp;  wsp += (size_t)BT_ * H_ * 2;
    short* vT = (short*)wsp;  wsp += (size_t)BT_ * H_ * 2;
    short* ao = (short*)wsp;  wsp += (size_t)BT_ * H_ * 2;
    short* mid = (short*)wsp; wsp += (size_t)BT_ * F_ * 2;
    short* WqkvT = (short*)wsp; wsp += (size_t)NL_ * 3 * H_ * H_ * 2;
    short* WoT = (short*)wsp;   wsp += (size_t)NL_ * H_ * H_ * 2;
    short* W1T = (short*)wsp;   wsp += (size_t)NL_ * H_ * F_ * 2;
    short* W2T = (short*)wsp;   wsp += (size_t)NL_ * F_ * H_ * 2;
    short* WhT = (short*)wsp;   wsp += (size_t)H_ * V_ * 2;

    dim3 blk(256);
    k_cvt_all<<<dim3(14144), blk, 0, stream>>>(Wq, Wk, Wv, Wo, W1, W2, Whead,
                                               WqkvT, WoT, W1T, W2T, WhT);
    k_embed_ln<<<BT_, blk, 0, stream>>>(prefix, ids, emb, g1, b1, x, h);
    for (int l = 0; l < NL_; ++l) {
        size_t o1 = (size_t)l * H_ * H_;
        size_t oq = (size_t)l * 3 * H_ * H_;
        size_t o2 = (size_t)l * H_ * F_;
        k_gemm<3, false, false, 1><<<dim3(576), blk, 0, stream>>>(
            h, WqkvT + oq, nullptr, qb, kb, vT, BT_, 3 * H_, H_, 1.f);
        k_attn<<<dim3(T_ / 64, HEADS_, B_), blk, 0, stream>>>(qb, kb, vT, ao);
        k_gemm<0, false, false, 4><<<dim3(768), blk, 0, stream>>>(
            ao, WoT + o1, nullptr, p, nullptr, nullptr, BT_, H_, H_, 1.f);
        k_add_ln<<<BT_, blk, 0, stream>>>(x, p, g2 + l * H_, b2 + l * H_, h);
        k_gemm<1, true, true, 1><<<dim3(768), blk, 0, stream>>>(
            h, W1T + o2, bm1 + (size_t)l * F_, mid, nullptr, nullptr, BT_, F_, H_, 1.f);
        k_gemm<0, true, false, 4><<<dim3(768), blk, 0, stream>>>(
            mid, W2T + o2, bm2 + (size_t)l * H_, p, nullptr, nullptr, BT_, H_, F_, 1.f);
        const float* gn = (l + 1 < NL_) ? g1 + (l + 1) * H_ : gf;
        const float* bn = (l + 1 < NL_) ? b1 + (l + 1) * H_ : bf;
        k_add_ln<<<BT_, blk, 0, stream>>>(x, p, gn, bn, h);
    }
    // head GEMM: persistent 8-phase kernel, grid MUST be 256 (chunk math)
    k_gemm8<<<dim3(256), dim3(512), 0, stream>>>(h, WhT, out, BT_, V_, H_);
}